// Round 5
// baseline (379.807 us; speedup 1.0000x reference)
//
#include <hip/hip_runtime.h>

// MultiHeadAttentionBlock: B=4, S=2048, D=1024, H=16, DK=64
// Pipeline: cvt(w); cvt(q,k,v) [k,v staged in d_out - dead until final gemm];
// batched QKV gemm (1 dispatch, 1536 blocks); flash attention (transposed,
// no-max softmax, 2-stage intra-wave pipeline); out gemm -> fp32.
// All matmuls: bf16 MFMA 16x16x32, fp32 accumulate, GLL16 staging.
//
// Verified MFMA layouts (learn_hip m89/m91):
//   A-operand: lane holds A[m=lane&15][k=(lane>>4)*8 + j], j=0..7 (16B contiguous)
//   B-operand: lane holds B^T-row n=lane&15 along k (same shape as A)
//   C/D:       col = lane&15 (B index), row = (lane>>4)*4 + reg (A index)

typedef __attribute__((ext_vector_type(8))) short bf16x8;
typedef __attribute__((ext_vector_type(4))) float f32x4;
typedef unsigned int u32;

#define DEVI __device__ __forceinline__

static constexpr int S_LEN = 2048;
static constexpr int NH = 16;
static constexpr int DK = 64;
// scores scale folded into Q projection: (1/sqrt(64)) * log2(e)
static constexpr float Q_SCALE = 0.125f * 1.44269504088896340736f;

DEVI unsigned short f2b(float f) {  // fp32 -> bf16 round-to-nearest-even
    unsigned int u = __builtin_bit_cast(unsigned int, f);
    u += 0x7fffu + ((u >> 16) & 1u);
    return (unsigned short)(u >> 16);
}

// pack two fp32 -> bf16x2 in one HW inst when available (gfx950 v_cvt_pk_bf16_f32)
DEVI u32 pkbf16(float a, float b) {
#if __has_builtin(__builtin_amdgcn_cvt_pk_bf16_f32)
    auto r = __builtin_amdgcn_cvt_pk_bf16_f32(a, b);
    return __builtin_bit_cast(u32, r);
#else
    return (u32)f2b(a) | ((u32)f2b(b) << 16);
#endif
}

// raw v_exp_f32: no OCML denormal/range fixup (inputs here are |x| <~ 12;
// denormal-result flush-to-zero is correct behavior for softmax weights)
DEVI float fexp2(float x) {
#if __has_builtin(__builtin_amdgcn_exp2f)
    return __builtin_amdgcn_exp2f(x);
#else
    return exp2f(x);
#endif
}

DEVI f32x4 mfma16(bf16x8 a, bf16x8 b, f32x4 c) {
    return __builtin_amdgcn_mfma_f32_16x16x32_bf16(a, b, c, 0, 0, 0);
}

#define GLL16(g, l)                                                        \
    __builtin_amdgcn_global_load_lds(                                      \
        (const __attribute__((address_space(1))) u32*)(g),                 \
        (__attribute__((address_space(3))) u32*)(l), 16, 0, 0)

// ---------------------------------------------------------------------------
// fp32 -> bf16 converters (memory-bound)
// ---------------------------------------------------------------------------
__global__ __launch_bounds__(256) void cvt3(
    const float* __restrict__ q, const float* __restrict__ k,
    const float* __restrict__ v, unsigned short* __restrict__ dq,
    unsigned short* __restrict__ dk, unsigned short* __restrict__ dv) {
    const int z = blockIdx.y;
    const float* src = z == 0 ? q : z == 1 ? k : v;
    unsigned short* dst = z == 0 ? dq : z == 1 ? dk : dv;
    long i = ((long)blockIdx.x * 256 + threadIdx.x) * 8;
    float4 v0 = *(const float4*)(src + i);
    float4 v1 = *(const float4*)(src + i + 4);
    uint4 o;
    o.x = pkbf16(v0.x, v0.y);
    o.y = pkbf16(v0.z, v0.w);
    o.z = pkbf16(v1.x, v1.y);
    o.w = pkbf16(v1.z, v1.w);
    *(uint4*)(dst + i) = o;
}

__global__ __launch_bounds__(256) void cvt_w(
    const float* __restrict__ a, const float* __restrict__ b,
    const float* __restrict__ c, const float* __restrict__ d,
    unsigned short* __restrict__ o) {
    const float* src = blockIdx.y == 0 ? a : blockIdx.y == 1 ? b
                     : blockIdx.y == 2 ? c : d;
    unsigned short* dst = o + (long)blockIdx.y * 1048576;
    long i = ((long)blockIdx.x * 256 + threadIdx.x) * 8;
    float4 v0 = *(const float4*)(src + i);
    float4 v1 = *(const float4*)(src + i + 4);
    uint4 ov;
    ov.x = pkbf16(v0.x, v0.y);
    ov.y = pkbf16(v0.z, v0.w);
    ov.z = pkbf16(v1.x, v1.y);
    ov.w = pkbf16(v1.z, v1.w);
    *(uint4*)(dst + i) = ov;
}

// ---------------------------------------------------------------------------
// Batched QKV GEMM: z=0: qh=(q@wq^T+bq)*Q_SCALE  [B,H,S,DK]
//                   z=1: kh= k@wk^T+bk           [B,H,S,DK]
//                   z=2: vht=(v@wv^T+bv)^T       [B,H,DK,S]
// 128x128 tile, BK=32, GLL16 double-buffered, XOR-swizzled LDS.
// ---------------------------------------------------------------------------
__global__ __launch_bounds__(256) void gemm_qkv(
    const unsigned short* __restrict__ aq, const unsigned short* __restrict__ ak,
    const unsigned short* __restrict__ av, const unsigned short* __restrict__ wqkv,
    const float* __restrict__ bq, const float* __restrict__ bk,
    const float* __restrict__ bv, unsigned short* __restrict__ qh,
    unsigned short* __restrict__ kh, unsigned short* __restrict__ vht) {
    __shared__ __align__(16) unsigned short As[2][128 * 32];
    __shared__ __align__(16) unsigned short Bs[2][128 * 32];
    const int tid = threadIdx.x;
    const int w = tid >> 6, l = tid & 63, l16 = l & 15, quad = l >> 4;
    const int wm = (w >> 1) * 64, wn = (w & 1) * 64;
    const int m0 = blockIdx.y * 128, n0 = blockIdx.x * 128;
    const int z = blockIdx.z;
    const unsigned short* A = z == 0 ? aq : z == 1 ? ak : av;
    const unsigned short* W = wqkv + (long)z * 1048576;
    const float* bias = z == 0 ? bq : z == 1 ? bk : bv;

    f32x4 acc[4][4] = {};

    auto stage = [&](int kt, int buf) {
        #pragma unroll
        for (int h = 0; h < 2; ++h) {
            int sb = h * 256 + w * 64;
            int slot = sb + l;
            int row = slot >> 2, c = (slot & 3) ^ ((row >> 1) & 3);
            GLL16(A + (long)(m0 + row) * 1024 + kt + c * 8, &As[buf][sb * 8]);
            GLL16(W + (long)(n0 + row) * 1024 + kt + c * 8, &Bs[buf][sb * 8]);
        }
    };

    stage(0, 0);
    __syncthreads();

    for (int ki = 0; ki < 32; ++ki) {
        if (ki < 31) stage((ki + 1) * 32, (ki + 1) & 1);
        const unsigned short* as = As[ki & 1];
        const unsigned short* bs = Bs[ki & 1];
        bf16x8 a[4], b[4];
        #pragma unroll
        for (int i = 0; i < 4; ++i) {
            int r = wm + i * 16 + l16;
            a[i] = *(const bf16x8*)(as + (r * 4 + (quad ^ ((r >> 1) & 3))) * 8);
        }
        #pragma unroll
        for (int j = 0; j < 4; ++j) {
            int r = wn + j * 16 + l16;
            b[j] = *(const bf16x8*)(bs + (r * 4 + (quad ^ ((r >> 1) & 3))) * 8);
        }
        #pragma unroll
        for (int i = 0; i < 4; ++i)
            #pragma unroll
            for (int j = 0; j < 4; ++j)
                acc[i][j] = mfma16(a[i], b[j], acc[i][j]);
        __syncthreads();  // drains GLL16 vmcnt + protects buf reuse
    }

    if (z < 2) {
        unsigned short* out = z == 0 ? qh : kh;
        const float scale = z == 0 ? Q_SCALE : 1.0f;
        #pragma unroll
        for (int j = 0; j < 4; ++j) {
            int n = n0 + wn + j * 16 + l16;
            float bvl = bias[n];
            int hh = n >> 6, dd = n & 63;
            #pragma unroll
            for (int i = 0; i < 4; ++i)
                #pragma unroll
                for (int r = 0; r < 4; ++r) {
                    int m = m0 + wm + i * 16 + quad * 4 + r;
                    int bb = m >> 11, ss = m & 2047;
                    out[(((long)(bb * NH + hh) * S_LEN + ss) * DK) + dd] =
                        f2b((acc[i][j][r] + bvl) * scale);
                }
        }
    } else {
        unsigned short* out = vht;  // [bh][d][s]
        #pragma unroll
        for (int j = 0; j < 4; ++j) {
            int n = n0 + wn + j * 16 + l16;
            float bvl = bias[n];
            int hh = n >> 6, dd = n & 63;
            #pragma unroll
            for (int i = 0; i < 4; ++i) {
                int m = m0 + wm + i * 16 + quad * 4;  // r=0..3 contiguous in s
                int bb = m >> 11, ss = m & 2047;
                uint2 pk;
                pk.x = pkbf16(acc[i][j][0] + bvl, acc[i][j][1] + bvl);
                pk.y = pkbf16(acc[i][j][2] + bvl, acc[i][j][3] + bvl);
                *(uint2*)(out + ((long)(bb * NH + hh) * DK + dd) * S_LEN + ss) = pk;
            }
        }
    }
}

// ---------------------------------------------------------------------------
// Output GEMM: fp32 out[m,n] = ctx@wo^T + bo
// ---------------------------------------------------------------------------
__global__ __launch_bounds__(256) void gemm_out(
    const unsigned short* __restrict__ A, const unsigned short* __restrict__ W,
    const float* __restrict__ bias, float* __restrict__ out) {
    __shared__ __align__(16) unsigned short As[2][128 * 32];
    __shared__ __align__(16) unsigned short Bs[2][128 * 32];
    const int tid = threadIdx.x;
    const int w = tid >> 6, l = tid & 63, l16 = l & 15, quad = l >> 4;
    const int wm = (w >> 1) * 64, wn = (w & 1) * 64;
    const int m0 = blockIdx.y * 128, n0 = blockIdx.x * 128;

    f32x4 acc[4][4] = {};

    auto stage = [&](int kt, int buf) {
        #pragma unroll
        for (int h = 0; h < 2; ++h) {
            int sb = h * 256 + w * 64;
            int slot = sb + l;
            int row = slot >> 2, c = (slot & 3) ^ ((row >> 1) & 3);
            GLL16(A + (long)(m0 + row) * 1024 + kt + c * 8, &As[buf][sb * 8]);
            GLL16(W + (long)(n0 + row) * 1024 + kt + c * 8, &Bs[buf][sb * 8]);
        }
    };

    stage(0, 0);
    __syncthreads();

    for (int ki = 0; ki < 32; ++ki) {
        if (ki < 31) stage((ki + 1) * 32, (ki + 1) & 1);
        const unsigned short* as = As[ki & 1];
        const unsigned short* bs = Bs[ki & 1];
        bf16x8 a[4], b[4];
        #pragma unroll
        for (int i = 0; i < 4; ++i) {
            int r = wm + i * 16 + l16;
            a[i] = *(const bf16x8*)(as + (r * 4 + (quad ^ ((r >> 1) & 3))) * 8);
        }
        #pragma unroll
        for (int j = 0; j < 4; ++j) {
            int r = wn + j * 16 + l16;
            b[j] = *(const bf16x8*)(bs + (r * 4 + (quad ^ ((r >> 1) & 3))) * 8);
        }
        #pragma unroll
        for (int i = 0; i < 4; ++i)
            #pragma unroll
            for (int j = 0; j < 4; ++j)
                acc[i][j] = mfma16(a[i], b[j], acc[i][j]);
        __syncthreads();
    }

    #pragma unroll
    for (int j = 0; j < 4; ++j) {
        int n = n0 + wn + j * 16 + l16;
        float bv = bias[n];
        #pragma unroll
        for (int i = 0; i < 4; ++i)
            #pragma unroll
            for (int r = 0; r < 4; ++r) {
                int m = m0 + wm + i * 16 + quad * 4 + r;
                out[(long)m * 1024 + n] = acc[i][j][r] + bv;
            }
    }
}

// ---------------------------------------------------------------------------
// Flash attention, transposed formulation, 2-stage intra-wave pipeline.
//   S^T = K_tile . Q^T ; p = exp2(s) (Q pre-scaled, no max subtraction);
//   P 32-key halves through wave-private LDS rows; O^T = V^T . P^T.
//
// Round 4/5 (T15 mechanism): R3 showed barrier drain was NOT the residual
// (counted vmcnt = -3us); the serial chain QKT->exp2->pack->PV within each
// wave leaves MFMA idle during exp2 and VALU idle during MFMA (29+46=75%).
// Rotate one stage: step kt issues QKT(kt) MFMAs (async on matrix pipe),
// then runs exp2/pack/PV of kt-1 on VALU while QKT(kt) completes.
//  - two named score states sA/sB, compile-time parity (rule #20).
//  - K triple-buffered staged 2 ahead; V triple-buffered staged 1 ahead
//    (consumed 2 steps after issue). End-of-step s_waitcnt vmcnt(4)
//    (tail: 2,0) + raw s_barrier: every waited load has a full step in
//    flight. FIFO walk verified: end of step kt retires K[kt+1]^2+V[kt]^2.
//  - buffer races: step kt reads Kb[kt%3],Vb[(kt-1)%3]; writes
//    Kb[(kt+2)%3],Vb[(kt+1)%3] - all distinct mod 3; per-step barrier
//    keeps waves in the same step window.
// LDS: 24576 (Kb x3) + 24576 (Vb x3) + 11264 (P) = 60416 B -> 2 blocks/CU
// (occupancy is a proven non-lever here, R1).
// XCD swizzle kept (FETCH at compulsory ~24.6 MB).
// R5 = R4 resubmitted unchanged: container failed (infra); static audit
// (barrier uniformity, vmcnt FIFO, mod-3 buffer disjointness, bounds) clean.
// ---------------------------------------------------------------------------
__global__ __launch_bounds__(256, 2) void attn(
    const unsigned short* __restrict__ qh, const unsigned short* __restrict__ kh,
    const unsigned short* __restrict__ vht, unsigned short* __restrict__ ctx) {
    __shared__ __align__(16) unsigned short Kb[3][4096];   // [64 keys][64 d] swz
    __shared__ __align__(16) unsigned short Vb[3][4096];   // [64 d][64 keys] swz
    __shared__ __align__(16) unsigned short P[128 * 44];

    // XCD-aware swizzle: 1024 blocks, 1024 % 8 == 0 -> bijective.
    // 128 blocks/XCD = 8 heads x 16 q-tiles (head's K/V panel L2-resident).
    const int id = blockIdx.y * 16 + blockIdx.x;
    const int id2 = (id & 7) * 128 + (id >> 3);
    const int qt = id2 & 15, bh = id2 >> 4;
    const int tid = threadIdx.x;
    const int w = tid >> 6, l = tid & 63, l16 = l & 15, quad = l >> 4;

    const unsigned short* kh_b = kh + (long)bh * 2048 * 64;
    const unsigned short* vh_b = vht + (long)bh * 64 * 2048;

    const unsigned short* qsrc = qh + ((long)bh * 2048 + qt * 128) * 64;
    bf16x8 qf[2][2];
    #pragma unroll
    for (int dd = 0; dd < 2; ++dd)
        #pragma unroll
        for (int i = 0; i < 2; ++i)
            qf[dd][i] = *(const bf16x8*)(qsrc + (w * 32 + i * 16 + l16) * 64 +
                                         dd * 32 + quad * 8);
    // Force Q loads resolved here (prologue), keeping main loop vmcnt clean.
    #pragma unroll
    for (int dd = 0; dd < 2; ++dd)
        #pragma unroll
        for (int i = 0; i < 2; ++i)
            asm volatile("" :: "v"(qf[dd][i]));
    __builtin_amdgcn_sched_barrier(0);

    // stage K tile (64 rows x 64 d = 512 slots of 16B, 2 per thread)
    auto stage_k = [&](const unsigned short* base, int buf) {
        #pragma unroll
        for (int rr = 0; rr < 2; ++rr) {
            int sb = rr * 256 + w * 64;
            int slot = sb + l;
            int row = slot >> 3, cc = (slot & 7) ^ (row & 7);
            GLL16(base + (long)row * 64 + cc * 8, &Kb[buf][sb * 8]);
        }
    };
    // stage V^T tile (64 d x 64 keys)
    auto stage_v = [&](const unsigned short* vbase, int buf) {
        #pragma unroll
        for (int rr = 0; rr < 2; ++rr) {
            int sb = rr * 256 + w * 64;
            int slot = sb + l;
            int d = slot >> 3, cc = (slot & 7) ^ (d & 7);
            GLL16(vbase + (long)d * 2048 + cc * 8, &Vb[buf][sb * 8]);
        }
    };

    f32x4 o[4][2] = {};
    f32x4 osum[2] = {};
    bf16x8 ones;
    #pragma unroll
    for (int j = 0; j < 8; ++j) ones[j] = (short)0x3f80;  // bf16 1.0

    f32x4 sA[2][4], sB[2][4];

    // issue QK^T for one K-tile into sa (MFMA async; results consumed by fin
    // one step later)
    auto qkt = [&](const unsigned short* kb, f32x4 (&sa)[2][4]) {
        #pragma unroll
        for (int i = 0; i < 2; ++i)
            #pragma unroll
            for (int ja = 0; ja < 4; ++ja)
                sa[i][ja] = f32x4{0.f, 0.f, 0.f, 0.f};
        #pragma unroll
        for (int dd = 0; dd < 2; ++dd) {
            bf16x8 kf[4];
            #pragma unroll
            for (int ja = 0; ja < 4; ++ja) {
                int row = ja * 16 + l16;
                kf[ja] = *(const bf16x8*)(kb + (row * 8 + ((dd * 4 + quad) ^ (row & 7))) * 8);
            }
            __builtin_amdgcn_s_setprio(1);
            #pragma unroll
            for (int i = 0; i < 2; ++i)
                #pragma unroll
                for (int ja = 0; ja < 4; ++ja)
                    sa[i][ja] = mfma16(kf[ja], qf[dd][i], sa[i][ja]);
            __builtin_amdgcn_s_setprio(0);
        }
    };

    // softmax-finish + PV for the previous step's scores
    auto fin = [&](f32x4 (&sa)[2][4], const unsigned short* vb) {
        #pragma unroll
        for (int i = 0; i < 2; ++i)
            #pragma unroll
            for (int ja = 0; ja < 4; ++ja)
                #pragma unroll
                for (int r = 0; r < 4; ++r)
                    sa[i][ja][r] = fexp2(sa[i][ja][r]);
        #pragma unroll
        for (int qtr = 0; qtr < 2; ++qtr) {
            #pragma unroll
            for (int jh = 0; jh < 2; ++jh)
                #pragma unroll
                for (int i = 0; i < 2; ++i) {
                    int row = w * 32 + i * 16 + l16;
                    int ja = qtr * 2 + jh;
                    uint2 pk;
                    pk.x = pkbf16(sa[i][ja][0], sa[i][ja][1]);
                    pk.y = pkbf16(sa[i][ja][2], sa[i][ja][3]);
                    *(uint2*)(&P[row * 44 + jh * 16 + quad * 4]) = pk;
                }
            bf16x8 vf[4], pf[2];
            #pragma unroll
            for (int jd = 0; jd < 4; ++jd) {
                int d = jd * 16 + l16;
                vf[jd] = *(const bf16x8*)(vb + (d * 8 + ((qtr * 4 + quad) ^ (d & 7))) * 8);
            }
            #pragma unroll
            for (int i = 0; i < 2; ++i) {
                int row = w * 32 + i * 16 + l16;
                pf[i] = *(const bf16x8*)(&P[row * 44 + quad * 8]);
            }
            __builtin_amdgcn_s_setprio(1);
            #pragma unroll
            for (int jd = 0; jd < 4; ++jd)
                #pragma unroll
                for (int i = 0; i < 2; ++i)
                    o[jd][i] = mfma16(vf[jd], pf[i], o[jd][i]);
            #pragma unroll
            for (int i = 0; i < 2; ++i)
                osum[i] = mfma16(ones, pf[i], osum[i]);  // row-sum on MFMA pipe
            __builtin_amdgcn_s_setprio(0);
        }
    };

    // prologue: K0,V0,K1,V1,K2 staged; full drain (once); QKT(0); barrier
    // (second barrier protects Kb[0] against step 1's stage of K3->Kb[0]).
    stage_k(kh_b, 0);
    stage_v(vh_b, 0);
    stage_k(kh_b + 4096, 1);
    stage_v(vh_b + 64, 1);
    stage_k(kh_b + 8192, 2);
    asm volatile("s_waitcnt vmcnt(0)" ::: "memory");
    __builtin_amdgcn_s_barrier();
    __builtin_amdgcn_sched_barrier(0);
    qkt(Kb[0], sA);
    __builtin_amdgcn_s_barrier();
    __builtin_amdgcn_sched_barrier(0);

    const unsigned short* kstage = kh_b + 3 * 4096;  // K[3] base (u16 units)
    const unsigned short* vstage = vh_b + 2 * 64;    // V[2] base
    int kr = 1, kst = 0, vp = 0, vst = 2;  // = kt%3, (kt+2)%3, (kt-1)%3, (kt+1)%3 at kt=1

// one pipeline step kt: stage K[kt+2],V[kt+1]; issue QKT(kt)->CUR;
// finish(kt-1) from PRV; counted-vmcnt + barrier.
#define ATTN_STEP(CUR, PRV, DO_K, DO_V, VMC)                               \
    {                                                                      \
        if (DO_K) stage_k(kstage, kst);                                    \
        if (DO_V) stage_v(vstage, vst);                                    \
        kstage += 4096; vstage += 64;                                      \
        __builtin_amdgcn_sched_barrier(0);                                 \
        qkt(Kb[kr], CUR);                                                  \
        fin(PRV, Vb[vp]);                                                  \
        asm volatile("s_waitcnt vmcnt(" #VMC ")" ::: "memory");            \
        __builtin_amdgcn_s_barrier();                                      \
        __builtin_amdgcn_sched_barrier(0);                                 \
        kr = kr == 2 ? 0 : kr + 1;                                         \
        kst = kst == 2 ? 0 : kst + 1;                                      \
        vp = vp == 2 ? 0 : vp + 1;                                         \
        vst = vst == 2 ? 0 : vst + 1;                                      \
    }

    for (int t = 0; t < 14; ++t) {  // kt = 1..28
        ATTN_STEP(sB, sA, 1, 1, 4)
        ATTN_STEP(sA, sB, 1, 1, 4)
    }
    ATTN_STEP(sB, sA, 1, 1, 4)  // kt=29: stages K31,V30
    ATTN_STEP(sA, sB, 0, 1, 2)  // kt=30: stages V31
    ATTN_STEP(sB, sA, 0, 0, 0)  // kt=31
#undef ATTN_STEP
    fin(sB, Vb[vp]);  // finish(31); V31 in Vb[1], vp == 31%3 == 1 here

    const int b = bh >> 4, hh = bh & 15;
    #pragma unroll
    for (int i = 0; i < 2; ++i) {
        float inv = 1.0f / osum[i][0];  // rows of osum all equal; col = l16 = q
        int s = qt * 128 + w * 32 + i * 16 + l16;
        #pragma unroll
        for (int jd = 0; jd < 4; ++jd) {
            uint2 pk;
            pk.x = pkbf16(o[jd][i][0] * inv, o[jd][i][1] * inv);
            pk.y = pkbf16(o[jd][i][2] * inv, o[jd][i][3] * inv);
            *(uint2*)(&ctx[((long)(b * 2048 + s) * 1024) + hh * 64 + jd * 16 + quad * 4]) = pk;
        }
    }
}

extern "C" void kernel_launch(void* const* d_in, const int* in_sizes, int n_in,
                              void* d_out, int out_size, void* d_ws, size_t ws_size,
                              hipStream_t stream) {
    const float* q  = (const float*)d_in[0];
    const float* k  = (const float*)d_in[1];
    const float* v  = (const float*)d_in[2];
    const float* wq = (const float*)d_in[3];
    const float* bq = (const float*)d_in[4];
    const float* wk = (const float*)d_in[5];
    const float* bk = (const float*)d_in[6];
    const float* wv = (const float*)d_in[7];
    const float* bv = (const float*)d_in[8];
    const float* wo = (const float*)d_in[9];
    const float* bo = (const float*)d_in[10];
    float* out = (float*)d_out;

    // workspace (u16 units): ab_q(8M, reused as ctx) | qh(8M) | kh(8M) |
    // vht(8M) | weights 4x1M  = 36M u16 = 72 MB.
    // ab_k/ab_v live in d_out (32 MB fp32 = 16M u16), dead until gemm_out.
    const size_t NE = 8u * 1024u * 1024u;
    unsigned short* ab_q = (unsigned short*)d_ws;
    unsigned short* qh   = ab_q + NE;
    unsigned short* kh   = qh + NE;
    unsigned short* vht  = kh + NE;
    unsigned short* wb   = vht + NE;
    unsigned short* wob  = wb + 3 * 1048576;
    unsigned short* ctx  = ab_q;
    unsigned short* ab_k = (unsigned short*)d_out;
    unsigned short* ab_v = ab_k + NE;

    dim3 blk(256);
    cvt_w<<<dim3(512, 4), blk, 0, stream>>>(wq, wk, wv, wo, wb);
    cvt3<<<dim3(4096, 3), blk, 0, stream>>>(q, k, v, ab_q, ab_k, ab_v);
    gemm_qkv<<<dim3(8, 64, 3), blk, 0, stream>>>(ab_q, ab_k, ab_v, wb,
                                                 bq, bk, bv, qh, kh, vht);
    attn<<<dim3(16, 64), blk, 0, stream>>>(qh, kh, vht, ctx);
    gemm_out<<<dim3(8, 64), blk, 0, stream>>>(ctx, wob, bo, out);
}

// Round 6
// 365.503 us; speedup vs baseline: 1.0391x; 1.0391x over previous
//
#include <hip/hip_runtime.h>

// MultiHeadAttentionBlock: B=4, S=2048, D=1024, H=16, DK=64
// Pipeline: cvt(w); cvt(q,k,v) [k,v staged in d_out - dead until final gemm];
// batched QKV gemm (8-phase 256^2, 1 dispatch); flash attention (transposed,
// no-max softmax, R3 counted-vmcnt version); out gemm (8-phase 256^2) -> fp32.
// All matmuls: bf16 MFMA 16x16x32, fp32 accumulate, GLL16 staging.
//
// Verified MFMA layouts (learn_hip m89/m91):
//   A-operand: lane holds A[m=lane&15][k=(lane>>4)*8 + j], j=0..7 (16B contiguous)
//   B-operand: lane holds B^T-row n=lane&15 along k (same shape as A)
//   C/D:       col = lane&15 (B index), row = (lane>>4)*4 + reg (A index)

typedef __attribute__((ext_vector_type(8))) short bf16x8;
typedef __attribute__((ext_vector_type(4))) float f32x4;
typedef unsigned int u32;

#define DEVI __device__ __forceinline__

static constexpr int S_LEN = 2048;
static constexpr int NH = 16;
static constexpr int DK = 64;
// scores scale folded into Q projection: (1/sqrt(64)) * log2(e)
static constexpr float Q_SCALE = 0.125f * 1.44269504088896340736f;

DEVI unsigned short f2b(float f) {  // fp32 -> bf16 round-to-nearest-even
    unsigned int u = __builtin_bit_cast(unsigned int, f);
    u += 0x7fffu + ((u >> 16) & 1u);
    return (unsigned short)(u >> 16);
}

DEVI u32 pkbf16(float a, float b) {
#if __has_builtin(__builtin_amdgcn_cvt_pk_bf16_f32)
    auto r = __builtin_amdgcn_cvt_pk_bf16_f32(a, b);
    return __builtin_bit_cast(u32, r);
#else
    return (u32)f2b(a) | ((u32)f2b(b) << 16);
#endif
}

// raw v_exp_f32 (no OCML fixup; softmax weights tolerate denormal flush)
DEVI float fexp2(float x) {
#if __has_builtin(__builtin_amdgcn_exp2f)
    return __builtin_amdgcn_exp2f(x);
#else
    return exp2f(x);
#endif
}

DEVI f32x4 mfma16(bf16x8 a, bf16x8 b, f32x4 c) {
    return __builtin_amdgcn_mfma_f32_16x16x32_bf16(a, b, c, 0, 0, 0);
}

#define GLL16(g, l)                                                        \
    __builtin_amdgcn_global_load_lds(                                      \
        (const __attribute__((address_space(1))) u32*)(g),                 \
        (__attribute__((address_space(3))) u32*)(l), 16, 0, 0)

#define SBAR __builtin_amdgcn_sched_barrier(0)
#define PHB  SBAR; __builtin_amdgcn_s_barrier(); SBAR

// ---------------------------------------------------------------------------
// fp32 -> bf16 converters (memory-bound)
// ---------------------------------------------------------------------------
__global__ __launch_bounds__(256) void cvt3(
    const float* __restrict__ q, const float* __restrict__ k,
    const float* __restrict__ v, unsigned short* __restrict__ dq,
    unsigned short* __restrict__ dk, unsigned short* __restrict__ dv) {
    const int z = blockIdx.y;
    const float* src = z == 0 ? q : z == 1 ? k : v;
    unsigned short* dst = z == 0 ? dq : z == 1 ? dk : dv;
    long i = ((long)blockIdx.x * 256 + threadIdx.x) * 8;
    float4 v0 = *(const float4*)(src + i);
    float4 v1 = *(const float4*)(src + i + 4);
    uint4 o;
    o.x = pkbf16(v0.x, v0.y);
    o.y = pkbf16(v0.z, v0.w);
    o.z = pkbf16(v1.x, v1.y);
    o.w = pkbf16(v1.z, v1.w);
    *(uint4*)(dst + i) = o;
}

__global__ __launch_bounds__(256) void cvt_w(
    const float* __restrict__ a, const float* __restrict__ b,
    const float* __restrict__ c, const float* __restrict__ d,
    unsigned short* __restrict__ o) {
    const float* src = blockIdx.y == 0 ? a : blockIdx.y == 1 ? b
                     : blockIdx.y == 2 ? c : d;
    unsigned short* dst = o + (long)blockIdx.y * 1048576;
    long i = ((long)blockIdx.x * 256 + threadIdx.x) * 8;
    float4 v0 = *(const float4*)(src + i);
    float4 v1 = *(const float4*)(src + i + 4);
    uint4 ov;
    ov.x = pkbf16(v0.x, v0.y);
    ov.y = pkbf16(v0.z, v0.w);
    ov.z = pkbf16(v1.x, v1.y);
    ov.w = pkbf16(v1.z, v1.w);
    *(uint4*)(dst + i) = ov;
}

// ---------------------------------------------------------------------------
// 8-phase 256x256 GEMM core (m201 template, T2+T3+T4+T5), C = A @ W^T.
// A [M,1024] bf16 row-major, W [N,1024] bf16 row-major. BK=64, 8 waves
// (2M x 4N), per-wave output 128x64, acc[8][4]. LDS 128 KiB (2 dbuf).
//
// Stage chunks defined by CONSUMPTION phase (128 rows x 64 k = 2 GLL16/thr):
//   A-c0 = tile rows {0-63,128-191}   (read ph1: mi0-3 by both wm-halves)
//   A-c1 = tile rows {64-127,192-255} (read ph3: mi4-7)
//   B-c0 = tile rows = [0,32) mod 64  (read ph1: ni0-1 per wave)
//   B-c1 = tile rows = [32,64) mod 64 (read ph2: ni2-3)
// Staging schedule per iteration (tiles t0=2it [buf0], t1=2it+1 [buf1]):
//   ph1: t1-Ac1 -> buf1 (buf1's old Ac1 read prev ph7)
//   ph2: t2-Ac0 -> buf0 (Ac0 read ph1)   ph3: t2-Bc0 (Bc0 read ph1)
//   ph4: t2-Bc1 (Bc1 read ph2); vmcnt(6) retires ALL t1 -> ph5-8 read t1 safe
//   ph5: t2-Ac1 (Ac1 read ph3)           ph6: t3-Ac0 (buf1 Ac0 read ph5)
//   ph7: t3-Bc0 (read ph5)               ph8: t3-Bc1 (read ph6); vmcnt(6)
//        retires ALL t2 -> next ph1-4 read t2 safe. 3 chunks (6 loads) fly.
// Every stage lands >=1 full barrier after its target region's last read.
// Prologue: t0 all + t1{Ac0,Bc0,Bc1}; vmcnt(6) retires t0. Tail it=7: only
// ph1 (t15-Ac1), vmcnt(0) at ph4.
// ---------------------------------------------------------------------------
#define MM8(MH, NH, BB)                                                    \
    __builtin_amdgcn_s_setprio(1);                                         \
    _Pragma("unroll") for (int mi = 0; mi < 4; ++mi)                       \
        _Pragma("unroll") for (int ni = 0; ni < 2; ++ni)                   \
            _Pragma("unroll") for (int kk = 0; kk < 2; ++kk)               \
                acc[(MH)*4 + mi][(NH)*2 + ni] = mfma16(                    \
                    a[mi][kk], BB[ni][kk], acc[(MH)*4 + mi][(NH)*2 + ni]); \
    __builtin_amdgcn_s_setprio(0);

DEVI void gemm256_core(const unsigned short* __restrict__ Am,
                       const unsigned short* __restrict__ Wm,
                       int m0, int n0, int tid, f32x4 (&acc)[8][4]) {
    __shared__ __align__(16) unsigned short As[2][256 * 64];
    __shared__ __align__(16) unsigned short Bs[2][256 * 64];
    const int wid = tid >> 6, l = tid & 63, l16 = l & 15, quad = l >> 4;
    const int swz = l16 & 7;
    const int wm = (wid >> 2) * 128, wn = (wid & 3) * 64;
    unsigned short *As0 = &As[0][0], *As1 = &As[1][0];
    unsigned short *Bs0 = &Bs[0][0], *Bs1 = &Bs[1][0];

    bf16x8 a[4][2], b0[2][2], b1[2][2];

    // stage one chunk: type 0=Ac0 1=Ac1 2=Bc0 3=Bc1. LDS linear [256][64]
    // row-major; source k-chunk pre-swizzled by (l&7)^(row&7) so a swizzled
    // ds_read recovers linear k (rule #21: swizzle source+read, dest linear).
    auto stg = [&](const unsigned short* Mat, int r0, int ko,
                   unsigned short* lds, int type) {
        #pragma unroll
        for (int pass = 0; pass < 2; ++pass) {
            int wlr = pass * 64 + wid * 8;  // wave-uniform block of 8 lds-rows
            int row0 = type == 0 ? (wlr < 64 ? wlr : wlr + 64)
                     : type == 1 ? 64 + (wlr < 64 ? wlr : wlr + 64)
                     : type == 2 ? (wlr & 31) + (wlr >> 5) * 64
                                 : 32 + (wlr & 31) + (wlr >> 5) * 64;
            int row = row0 + (l >> 3);
            int cl = (l & 7) ^ (l >> 3);  // src chunk = lds chunk ^ (row&7)
            GLL16(Mat + (long)(r0 + row) * 1024 + ko + cl * 8, lds + row0 * 64);
        }
    };
    auto lda = [&](const unsigned short* as, int mh) {
        #pragma unroll
        for (int mi = 0; mi < 4; ++mi)
            #pragma unroll
            for (int kk = 0; kk < 2; ++kk)
                a[mi][kk] = *(const bf16x8*)(as +
                    (wm + (mh * 4 + mi) * 16 + l16) * 64 +
                    (((kk * 4 + quad) ^ swz) << 3));
    };
    auto ldb = [&](const unsigned short* bs, int nh, bf16x8 (&bb)[2][2]) {
        #pragma unroll
        for (int ni = 0; ni < 2; ++ni)
            #pragma unroll
            for (int kk = 0; kk < 2; ++kk)
                bb[ni][kk] = *(const bf16x8*)(bs +
                    (wn + (nh * 2 + ni) * 16 + l16) * 64 +
                    (((kk * 4 + quad) ^ swz) << 3));
    };

    // prologue: t0 fully, t1 {Ac0,Bc0,Bc1}; vmcnt(6) retires t0's 8 loads.
    stg(Am, m0, 0, As0, 0); stg(Wm, n0, 0, Bs0, 2);
    stg(Wm, n0, 0, Bs0, 3); stg(Am, m0, 0, As0, 1);
    stg(Am, m0, 64, As1, 0); stg(Wm, n0, 64, Bs1, 2); stg(Wm, n0, 64, Bs1, 3);
    asm volatile("s_waitcnt vmcnt(6)" ::: "memory");
    __builtin_amdgcn_s_barrier(); SBAR;

    #pragma unroll 1
    for (int it = 0; it < 8; ++it) {
        const bool F = it < 7;
        const int ko1 = it * 128 + 64, ko2 = it * 128 + 128, ko3 = it * 128 + 192;
        // ph1: compute t0 quadrant (mh0,nh0)
        lda(As0, 0); ldb(Bs0, 0, b0);
        stg(Am, m0, ko1, As1, 1);
        PHB; MM8(0, 0, b0); PHB;
        // ph2: (mh0,nh1)
        ldb(Bs0, 1, b1);
        if (F) stg(Am, m0, ko2, As0, 0);
        PHB; MM8(0, 1, b1); PHB;
        // ph3: (mh1,nh0)
        lda(As0, 1);
        if (F) stg(Wm, n0, ko2, Bs0, 2);
        PHB; MM8(1, 0, b0); PHB;
        // ph4: (mh1,nh1); K-tile boundary vmcnt
        if (F) stg(Wm, n0, ko2, Bs0, 3);
        PHB; MM8(1, 1, b1);
        SBAR;
        if (F) { asm volatile("s_waitcnt vmcnt(6)" ::: "memory"); }
        else   { asm volatile("s_waitcnt vmcnt(0)" ::: "memory"); }
        __builtin_amdgcn_s_barrier(); SBAR;
        // ph5: t1 (mh0,nh0)
        lda(As1, 0); ldb(Bs1, 0, b0);
        if (F) stg(Am, m0, ko2, As0, 1);
        PHB; MM8(0, 0, b0); PHB;
        // ph6: (mh0,nh1)
        ldb(Bs1, 1, b1);
        if (F) stg(Am, m0, ko3, As1, 0);
        PHB; MM8(0, 1, b1); PHB;
        // ph7: (mh1,nh0)
        lda(As1, 1);
        if (F) stg(Wm, n0, ko3, Bs1, 2);
        PHB; MM8(1, 0, b0); PHB;
        // ph8: (mh1,nh1); K-tile boundary vmcnt
        if (F) stg(Wm, n0, ko3, Bs1, 3);
        PHB; MM8(1, 1, b1);
        SBAR;
        if (F) { asm volatile("s_waitcnt vmcnt(6)" ::: "memory"); }
        __builtin_amdgcn_s_barrier(); SBAR;
    }
}

// ---------------------------------------------------------------------------
// Batched QKV GEMM: z=0: qh=(q@wq^T+bq)*Q_SCALE  [B,H,S,DK]
//                   z=1: kh= k@wk^T+bk           [B,H,S,DK]
//                   z=2: vht=(v@wv^T+bv)^T       [B,H,DK,S]
// ---------------------------------------------------------------------------
__global__ __launch_bounds__(512, 2) void gemm_qkv(
    const unsigned short* __restrict__ aq, const unsigned short* __restrict__ ak,
    const unsigned short* __restrict__ av, const unsigned short* __restrict__ wqkv,
    const float* __restrict__ bq, const float* __restrict__ bk,
    const float* __restrict__ bv, unsigned short* __restrict__ qh,
    unsigned short* __restrict__ kh, unsigned short* __restrict__ vht) {
    const int tid = threadIdx.x;
    const int wid = tid >> 6, l = tid & 63, l16 = l & 15, quad = l >> 4;
    const int wm = (wid >> 2) * 128, wn = (wid & 3) * 64;
    const int m0 = blockIdx.y * 256, n0 = blockIdx.x * 256;
    const int z = blockIdx.z;
    const unsigned short* Am = z == 0 ? aq : z == 1 ? ak : av;
    const unsigned short* Wm = wqkv + (long)z * 1048576;
    const float* bias = z == 0 ? bq : z == 1 ? bk : bv;

    f32x4 acc[8][4] = {};
    gemm256_core(Am, Wm, m0, n0, tid, acc);

    if (z < 2) {
        unsigned short* out = z == 0 ? qh : kh;
        const float scale = z == 0 ? Q_SCALE : 1.0f;
        #pragma unroll
        for (int ni = 0; ni < 4; ++ni) {
            int n = n0 + wn + ni * 16 + l16;
            float bvl = bias[n];
            int hh = n >> 6, dd = n & 63;
            #pragma unroll
            for (int mi = 0; mi < 8; ++mi)
                #pragma unroll
                for (int r = 0; r < 4; ++r) {
                    int m = m0 + wm + mi * 16 + quad * 4 + r;
                    int bb = m >> 11, ss = m & 2047;
                    out[(((long)(bb * NH + hh) * S_LEN + ss) * DK) + dd] =
                        f2b((acc[mi][ni][r] + bvl) * scale);
                }
        }
    } else {
        #pragma unroll
        for (int ni = 0; ni < 4; ++ni) {
            int n = n0 + wn + ni * 16 + l16;
            float bvl = bias[n];
            int hh = n >> 6, dd = n & 63;
            #pragma unroll
            for (int mi = 0; mi < 8; ++mi) {
                int m = m0 + wm + mi * 16 + quad * 4;  // r contiguous in s
                int bb = m >> 11, ss = m & 2047;
                uint2 pk;
                pk.x = pkbf16(acc[mi][ni][0] + bvl, acc[mi][ni][1] + bvl);
                pk.y = pkbf16(acc[mi][ni][2] + bvl, acc[mi][ni][3] + bvl);
                *(uint2*)(vht + ((long)(bb * NH + hh) * DK + dd) * S_LEN + ss) = pk;
            }
        }
    }
}

// ---------------------------------------------------------------------------
// Output GEMM: fp32 out[m,n] = ctx@wo^T + bo
// ---------------------------------------------------------------------------
__global__ __launch_bounds__(512, 2) void gemm_out(
    const unsigned short* __restrict__ A, const unsigned short* __restrict__ W,
    const float* __restrict__ bias, float* __restrict__ out) {
    const int tid = threadIdx.x;
    const int wid = tid >> 6, l = tid & 63, l16 = l & 15, quad = l >> 4;
    const int wm = (wid >> 2) * 128, wn = (wid & 3) * 64;
    const int m0 = blockIdx.y * 256, n0 = blockIdx.x * 256;

    f32x4 acc[8][4] = {};
    gemm256_core(A, W, m0, n0, tid, acc);

    #pragma unroll
    for (int ni = 0; ni < 4; ++ni) {
        int n = n0 + wn + ni * 16 + l16;
        float bv = bias[n];
        #pragma unroll
        for (int mi = 0; mi < 8; ++mi)
            #pragma unroll
            for (int r = 0; r < 4; ++r) {
                int m = m0 + wm + mi * 16 + quad * 4 + r;
                out[(long)m * 1024 + n] = acc[mi][ni][r] + bv;
            }
    }
}

// ---------------------------------------------------------------------------
// Flash attention — R3 version verbatim (proven 108.9 us; R4/R5 pipeline
// regressed and was reverted).  Transposed formulation: S^T = K.Q^T;
// p = exp2(s); P via wave-private LDS rows; O^T = V^T.P^T; lsum via
// ones-vector MFMA; K dbuf staged 1 ahead, V tri-buf staged 2 ahead;
// counted vmcnt(2) + raw barrier once per kt.
// LDS: 16384 (Kb x2) + 24576 (Vb x3) + 11264 (P) = 52224 B -> 3 blocks/CU.
// ---------------------------------------------------------------------------
__global__ __launch_bounds__(256, 3) void attn(
    const unsigned short* __restrict__ qh, const unsigned short* __restrict__ kh,
    const unsigned short* __restrict__ vht, unsigned short* __restrict__ ctx) {
    __shared__ __align__(16) unsigned short Kb[2][4096];   // [64 keys][64 d] swz
    __shared__ __align__(16) unsigned short Vb[3][4096];   // [64 d][64 keys] swz
    __shared__ __align__(16) unsigned short P[128 * 44];

    // XCD-aware swizzle: 1024 blocks, bijective; 128 blocks/XCD = 8 heads
    // x 16 q-tiles (head's K/V panel L2-resident). R1: FETCH 139->32 MB.
    const int id = blockIdx.y * 16 + blockIdx.x;
    const int id2 = (id & 7) * 128 + (id >> 3);
    const int qt = id2 & 15, bh = id2 >> 4;
    const int tid = threadIdx.x;
    const int w = tid >> 6, l = tid & 63, l16 = l & 15, quad = l >> 4;

    const unsigned short* kh_b = kh + (long)bh * 2048 * 64;
    const unsigned short* vh_b = vht + (long)bh * 64 * 2048;

    const unsigned short* qsrc = qh + ((long)bh * 2048 + qt * 128) * 64;
    bf16x8 qf[2][2];
    #pragma unroll
    for (int dd = 0; dd < 2; ++dd)
        #pragma unroll
        for (int i = 0; i < 2; ++i)
            qf[dd][i] = *(const bf16x8*)(qsrc + (w * 32 + i * 16 + l16) * 64 +
                                         dd * 32 + quad * 8);
    #pragma unroll
    for (int dd = 0; dd < 2; ++dd)
        #pragma unroll
        for (int i = 0; i < 2; ++i)
            asm volatile("" :: "v"(qf[dd][i]));

    auto stage_k = [&](const unsigned short* base, int buf) {
        #pragma unroll
        for (int rr = 0; rr < 2; ++rr) {
            int sb = rr * 256 + w * 64;
            int slot = sb + l;
            int row = slot >> 3, cc = (slot & 7) ^ (row & 7);
            GLL16(base + (long)row * 64 + cc * 8, &Kb[buf][sb * 8]);
        }
    };
    auto stage_v = [&](const unsigned short* vbase, int buf) {
        #pragma unroll
        for (int rr = 0; rr < 2; ++rr) {
            int sb = rr * 256 + w * 64;
            int slot = sb + l;
            int d = slot >> 3, cc = (slot & 7) ^ (d & 7);
            GLL16(vbase + (long)d * 2048 + cc * 8, &Vb[buf][sb * 8]);
        }
    };

    // prologue: K0, V0, V1 issued; wait K0+V0 (vmcnt(2) leaves V1 in flight)
    stage_k(kh_b, 0);
    stage_v(vh_b, 0);
    stage_v(vh_b + 64, 1);
    asm volatile("s_waitcnt vmcnt(2)" ::: "memory");
    __builtin_amdgcn_s_barrier();
    __builtin_amdgcn_sched_barrier(0);

    f32x4 o[4][2] = {};
    f32x4 osum[2] = {};
    bf16x8 ones;
    #pragma unroll
    for (int j = 0; j < 8; ++j) ones[j] = (short)0x3f80;  // bf16 1.0

    const unsigned short* kstage = kh_b + 64 * 64;   // K[1] base
    const unsigned short* vstage = vh_b + 2 * 64;    // V[2] base
    int vr = 0, vs = 2;  // V read / stage buffer (mod 3)
    for (int kt = 0; kt < 32; ++kt) {
        if (kt < 31) stage_k(kstage, (kt + 1) & 1);
        if (kt < 30) stage_v(vstage, vs);
        kstage += 64 * 64;
        vstage += 64;
        __builtin_amdgcn_sched_barrier(0);  // keep prefetch issue at loop top

        const unsigned short* kb = Kb[kt & 1];
        f32x4 sa[2][4] = {};
        #pragma unroll
        for (int dd = 0; dd < 2; ++dd) {
            bf16x8 kf[4];
            #pragma unroll
            for (int ja = 0; ja < 4; ++ja) {
                int row = ja * 16 + l16;
                kf[ja] = *(const bf16x8*)(kb + (row * 8 + ((dd * 4 + quad) ^ (row & 7))) * 8);
            }
            __builtin_amdgcn_s_setprio(1);
            #pragma unroll
            for (int i = 0; i < 2; ++i)
                #pragma unroll
                for (int ja = 0; ja < 4; ++ja)
                    sa[i][ja] = mfma16(kf[ja], qf[dd][i], sa[i][ja]);
            __builtin_amdgcn_s_setprio(0);
        }

        #pragma unroll
        for (int i = 0; i < 2; ++i)
            #pragma unroll
            for (int ja = 0; ja < 4; ++ja)
                #pragma unroll
                for (int r = 0; r < 4; ++r)
                    sa[i][ja][r] = fexp2(sa[i][ja][r]);

        // no barrier: V[kt] resident since end of kt-1; Vb[vs] is a
        // different buffer ((kt+2)%3 != kt%3).
        const unsigned short* vb = Vb[vr];
        #pragma unroll
        for (int qtr = 0; qtr < 2; ++qtr) {
            #pragma unroll
            for (int jh = 0; jh < 2; ++jh)
                #pragma unroll
                for (int i = 0; i < 2; ++i) {
                    int row = w * 32 + i * 16 + l16;
                    int ja = qtr * 2 + jh;
                    uint2 pk;
                    pk.x = pkbf16(sa[i][ja][0], sa[i][ja][1]);
                    pk.y = pkbf16(sa[i][ja][2], sa[i][ja][3]);
                    *(uint2*)(&P[row * 44 + jh * 16 + quad * 4]) = pk;
                }
            bf16x8 vf[4], pf[2];
            #pragma unroll
            for (int jd = 0; jd < 4; ++jd) {
                int d = jd * 16 + l16;
                vf[jd] = *(const bf16x8*)(vb + (d * 8 + ((qtr * 4 + quad) ^ (d & 7))) * 8);
            }
            #pragma unroll
            for (int i = 0; i < 2; ++i) {
                int row = w * 32 + i * 16 + l16;
                pf[i] = *(const bf16x8*)(&P[row * 44 + quad * 8]);
            }
            __builtin_amdgcn_s_setprio(1);
            #pragma unroll
            for (int jd = 0; jd < 4; ++jd)
                #pragma unroll
                for (int i = 0; i < 2; ++i)
                    o[jd][i] = mfma16(vf[jd], pf[i], o[jd][i]);
            #pragma unroll
            for (int i = 0; i < 2; ++i)
                osum[i] = mfma16(ones, pf[i], osum[i]);  // row-sum on MFMA pipe
            __builtin_amdgcn_s_setprio(0);
        }

        // end-of-kt sync: wait K[kt+1]+V[kt+1] landed, keep V[kt+2] in flight
        if (kt < 30) {
            asm volatile("s_waitcnt vmcnt(2)" ::: "memory");
        } else if (kt == 30) {
            asm volatile("s_waitcnt vmcnt(0)" ::: "memory");
        }
        if (kt < 31) {
            __builtin_amdgcn_s_barrier();
            __builtin_amdgcn_sched_barrier(0);
        }

        vr = (vr + 1 == 3) ? 0 : vr + 1;
        vs = (vs + 1 == 3) ? 0 : vs + 1;
    }

    const int b = bh >> 4, hh = bh & 15;
    #pragma unroll
    for (int i = 0; i < 2; ++i) {
        float inv = 1.0f / osum[i][0];  // rows of osum all equal; col = l16 = q
        int s = qt * 128 + w * 32 + i * 16 + l16;
        #pragma unroll
        for (int jd = 0; jd < 4; ++jd) {
            uint2 pk;
            pk.x = pkbf16(o[jd][i][0] * inv, o[jd][i][1] * inv);
            pk.y = pkbf16(o[jd][i][2] * inv, o[jd][i][3] * inv);
            *(uint2*)(&ctx[((long)(b * 2048 + s) * 1024) + hh * 64 + jd * 16 + quad * 4]) = pk;
        }
    }
}

extern "C" void kernel_launch(void* const* d_in, const int* in_sizes, int n_in,
                              void* d_out, int out_size, void* d_ws, size_t ws_size,
                              hipStream_t stream) {
    const float* q  = (const float*)d_in[0];
    const float* k  = (const float*)d_in[1];
    const float* v  = (const float*)d_in[2];
    const float* wq = (const float*)d_in[3];
    const float* bq = (const float*)d_in[4];
    const float* wk = (const float*)d_in[5];
    const float* bk = (const float*)d_in[6];
    const float* wv = (const float*)d_in[7];
    const float* bv = (const float*)d_in[8];
    const float* wo = (const float*)d_in[9];
    const float* bo = (const float*)d_in[10];
    float* out = (float*)d_out;

    // workspace (u16 units): ab_q(8M, reused as ctx) | qh(8M) | kh(8M) |
    // vht(8M) | weights 4x1M  = 36M u16 = 72 MB.
    // ab_k/ab_v live in d_out (32 MB fp32 = 16M u16), dead until gemm_out.
    const size_t NE = 8u * 1024u * 1024u;
    unsigned short* ab_q = (unsigned short*)d_ws;
    unsigned short* qh   = ab_q + NE;
    unsigned short* kh   = qh + NE;
    unsigned short* vht  = kh + NE;
    unsigned short* wb   = vht + NE;
    unsigned short* wob  = wb + 3 * 1048576;
    unsigned short* ctx  = ab_q;
    unsigned short* ab_k = (unsigned short*)d_out;
    unsigned short* ab_v = ab_k + NE;

    cvt_w<<<dim3(512, 4), dim3(256), 0, stream>>>(wq, wk, wv, wo, wb);
    cvt3<<<dim3(4096, 3), dim3(256), 0, stream>>>(q, k, v, ab_q, ab_k, ab_v);
    gemm_qkv<<<dim3(4, 32, 3), dim3(512), 0, stream>>>(ab_q, ab_k, ab_v, wb,
                                                       bq, bk, bv, qh, kh, vht);
    attn<<<dim3(16, 64), dim3(256), 0, stream>>>(qh, kh, vht, ctx);
    gemm_out<<<dim3(4, 32), dim3(512), 0, stream>>>(ctx, wob, bo, out);
}

// Round 7
// 345.724 us; speedup vs baseline: 1.0986x; 1.0572x over previous
//
#include <hip/hip_runtime.h>

// MultiHeadAttentionBlock: B=4, S=2048, D=1024, H=16, DK=64
// Pipeline: cvt_all (weights + q/k/v fp32->bf16, 1 dispatch); batched QKV
// gemm (256x128 8-phase-discipline, 768 blocks = 3 full CU rounds); flash
// attention (R3 proven version); out gemm (256x128, 256 blocks = 1 round).
// All matmuls: bf16 MFMA 16x16x32, fp32 accumulate, GLL16 staging.
//
// Verified MFMA layouts (learn_hip m89/m91):
//   A-operand: lane holds A[m=lane&15][k=(lane>>4)*8 + j], j=0..7 (16B contiguous)
//   B-operand: lane holds B^T-row n=lane&15 along k (same shape as A)
//   C/D:       col = lane&15 (B index), row = (lane>>4)*4 + reg (A index)

typedef __attribute__((ext_vector_type(8))) short bf16x8;
typedef __attribute__((ext_vector_type(4))) float f32x4;
typedef unsigned int u32;

#define DEVI __device__ __forceinline__

static constexpr int S_LEN = 2048;
static constexpr int NH = 16;
static constexpr int DK = 64;
// scores scale folded into Q projection: (1/sqrt(64)) * log2(e)
static constexpr float Q_SCALE = 0.125f * 1.44269504088896340736f;

DEVI unsigned short f2b(float f) {  // fp32 -> bf16 round-to-nearest-even
    unsigned int u = __builtin_bit_cast(unsigned int, f);
    u += 0x7fffu + ((u >> 16) & 1u);
    return (unsigned short)(u >> 16);
}

DEVI u32 pkbf16(float a, float b) {
#if __has_builtin(__builtin_amdgcn_cvt_pk_bf16_f32)
    auto r = __builtin_amdgcn_cvt_pk_bf16_f32(a, b);
    return __builtin_bit_cast(u32, r);
#else
    return (u32)f2b(a) | ((u32)f2b(b) << 16);
#endif
}

// raw v_exp_f32 (no OCML fixup; softmax weights tolerate denormal flush)
DEVI float fexp2(float x) {
#if __has_builtin(__builtin_amdgcn_exp2f)
    return __builtin_amdgcn_exp2f(x);
#else
    return exp2f(x);
#endif
}

DEVI f32x4 mfma16(bf16x8 a, bf16x8 b, f32x4 c) {
    return __builtin_amdgcn_mfma_f32_16x16x32_bf16(a, b, c, 0, 0, 0);
}

#define GLL16(g, l)                                                        \
    __builtin_amdgcn_global_load_lds(                                      \
        (const __attribute__((address_space(1))) u32*)(g),                 \
        (__attribute__((address_space(3))) u32*)(l), 16, 0, 0)

#define SBAR __builtin_amdgcn_sched_barrier(0)
#define PHB  SBAR; __builtin_amdgcn_s_barrier(); SBAR

// ---------------------------------------------------------------------------
// Fused fp32 -> bf16 converter: q/k/v (3 x 4096 blocks) + 4 weights
// (4 x 512 blocks) in ONE dispatch. 14336 blocks x 256 thr x 8 elems.
// ---------------------------------------------------------------------------
__global__ __launch_bounds__(256) void cvt_all(
    const float* __restrict__ q, const float* __restrict__ k,
    const float* __restrict__ v, const float* __restrict__ wq,
    const float* __restrict__ wk, const float* __restrict__ wv,
    const float* __restrict__ wo, unsigned short* __restrict__ dq,
    unsigned short* __restrict__ dk, unsigned short* __restrict__ dv,
    unsigned short* __restrict__ wb) {
    const int id = blockIdx.x;
    const float* src;
    unsigned short* dst;
    long i;
    if (id < 12288) {  // q/k/v: 4096 blocks each
        int z = id >> 12, x = id & 4095;
        src = z == 0 ? q : z == 1 ? k : v;
        dst = z == 0 ? dq : z == 1 ? dk : dv;
        i = ((long)x * 256 + threadIdx.x) * 8;
    } else {           // weights: 512 blocks each
        int wi = id - 12288;
        int z = wi >> 9, x = wi & 511;
        src = z == 0 ? wq : z == 1 ? wk : z == 2 ? wv : wo;
        dst = wb + (long)z * 1048576;
        i = ((long)x * 256 + threadIdx.x) * 8;
    }
    float4 v0 = *(const float4*)(src + i);
    float4 v1 = *(const float4*)(src + i + 4);
    uint4 o;
    o.x = pkbf16(v0.x, v0.y);
    o.y = pkbf16(v0.z, v0.w);
    o.z = pkbf16(v1.x, v1.y);
    o.w = pkbf16(v1.z, v1.w);
    *(uint4*)(dst + i) = o;
}

// ---------------------------------------------------------------------------
// 256x128 GEMM core (m201 phase discipline, T2+T3+T4+T5), C = A @ W^T.
// A [M,1024] bf16 row-major, W [N,1024] bf16 row-major. BK=64, 8 waves
// (2M x 4N), per-wave output 128x32, acc[8][2]. LDS 96 KiB (A 64K + B 32K).
//
// R7 granularity fix: 256x128 tile -> gemm_qkv 768 blocks = 3 FULL rounds
// (was 384 = 1.5 rounds, 75% util); gemm_out 256 = 1 round (was 128 = 50%).
// 16 MFMA/phase kept; B-fragments register-reused across both mh-phases.
//
// Stage chunks (consumption-defined; 2 GLL16/thread each):
//   A-c0 = tile rows {0-63,128-191}   (read mh0-phase)
//   A-c1 = tile rows {64-127,192-255} (read mh1-phase)
//   B    = all 128 rows               (read at mh0, reg-held through mh1)
// Per iter (t0=2it buf0, t1=2it+1 buf1), 4 phases:
//   ph1 (t0-mh0): stage B(t1->Bs1), Ac1(t1->As1)   [regions last read: prev it]
//   ph2 (t0-mh1): stage Ac0(t2->As0) [read ph1]; vmcnt(2) retires all t1
//   ph3 (t1-mh0): stage B(t2->Bs0), Ac1(t2->As0) [read ph1/ph2]
//   ph4 (t1-mh1): stage Ac0(t3->As1) [read ph3];  vmcnt(2) retires all t2
// FIFO walk: boundary outstanding = 8, vmcnt(2) leaves exactly next Ac0.
// Prologue: Ac0(t0),B(t0),Ac1(t0),Ac0(t1) = 8 loads; vmcnt(2) retires t0.
// Tail it=7: ph1 stages t15 {B,Ac1}; guards off t16+; vmcnt(0) at ph2.
// ---------------------------------------------------------------------------
#define MM16(MH)                                                           \
    __builtin_amdgcn_s_setprio(1);                                         \
    _Pragma("unroll") for (int mi = 0; mi < 4; ++mi)                       \
        _Pragma("unroll") for (int ni = 0; ni < 2; ++ni)                   \
            _Pragma("unroll") for (int kk = 0; kk < 2; ++kk)               \
                acc[(MH)*4 + mi][ni] = mfma16(                             \
                    a[mi][kk], b[ni][kk], acc[(MH)*4 + mi][ni]);           \
    __builtin_amdgcn_s_setprio(0);

DEVI void gemm_core(const unsigned short* __restrict__ Am,
                    const unsigned short* __restrict__ Wm,
                    int m0, int n0, int tid, f32x4 (&acc)[8][2]) {
    __shared__ __align__(16) unsigned short As[2][256 * 64];
    __shared__ __align__(16) unsigned short Bs[2][128 * 64];
    const int wid = tid >> 6, l = tid & 63, l16 = l & 15, quad = l >> 4;
    const int swz = l16 & 7;
    const int wm = (wid >> 2) * 128, wn = (wid & 3) * 32;
    unsigned short *As0 = &As[0][0], *As1 = &As[1][0];
    unsigned short *Bs0 = &Bs[0][0], *Bs1 = &Bs[1][0];

    bf16x8 a[4][2], b[2][2];

    // stage one chunk: type 0=Ac0 1=Ac1 2=B(full 128 rows). LDS linear
    // [rows][64] row-major; source k-chunk pre-swizzled by (l&7)^(l>>3)
    // (= lds-chunk ^ (row&7), row0 multiple of 8) so swizzled ds_read
    // recovers linear k (rule #21: swizzle source+read, dest linear).
    auto stg = [&](const unsigned short* Mat, int r0, int ko,
                   unsigned short* lds, int type) {
        #pragma unroll
        for (int pass = 0; pass < 2; ++pass) {
            int wlr = pass * 64 + wid * 8;  // wave-uniform block of 8 lds-rows
            int row0 = type == 0 ? (wlr < 64 ? wlr : wlr + 64)
                     : type == 1 ? 64 + (wlr < 64 ? wlr : wlr + 64)
                                 : wlr;
            int row = row0 + (l >> 3);
            int cl = (l & 7) ^ (l >> 3);
            GLL16(Mat + (long)(r0 + row) * 1024 + ko + cl * 8, lds + row0 * 64);
        }
    };
    auto lda = [&](const unsigned short* as, int mh) {
        #pragma unroll
        for (int mi = 0; mi < 4; ++mi)
            #pragma unroll
            for (int kk = 0; kk < 2; ++kk)
                a[mi][kk] = *(const bf16x8*)(as +
                    (wm + (mh * 4 + mi) * 16 + l16) * 64 +
                    (((kk * 4 + quad) ^ swz) << 3));
    };
    auto ldb = [&](const unsigned short* bs) {
        #pragma unroll
        for (int ni = 0; ni < 2; ++ni)
            #pragma unroll
            for (int kk = 0; kk < 2; ++kk)
                b[ni][kk] = *(const bf16x8*)(bs +
                    (wn + ni * 16 + l16) * 64 +
                    (((kk * 4 + quad) ^ swz) << 3));
    };

    // prologue: issue order Ac0(t0),B(t0),Ac1(t0),Ac0(t1); vmcnt(2) = t0 done
    stg(Am, m0, 0, As0, 0);
    stg(Wm, n0, 0, Bs0, 2);
    stg(Am, m0, 0, As0, 1);
    stg(Am, m0, 64, As1, 0);
    asm volatile("s_waitcnt vmcnt(2)" ::: "memory");
    __builtin_amdgcn_s_barrier(); SBAR;

    #pragma unroll 1
    for (int it = 0; it < 8; ++it) {
        const bool F = it < 7;
        const int ko1 = it * 128 + 64, ko2 = it * 128 + 128, ko3 = it * 128 + 192;
        // ph1: t0 mh0
        lda(As0, 0); ldb(Bs0);
        stg(Wm, n0, ko1, Bs1, 2);
        stg(Am, m0, ko1, As1, 1);
        PHB; MM16(0); PHB;
        // ph2: t0 mh1 (b reg-reused); boundary A
        lda(As0, 1);
        if (F) stg(Am, m0, ko2, As0, 0);
        PHB; MM16(1);
        SBAR;
        if (F) { asm volatile("s_waitcnt vmcnt(2)" ::: "memory"); }
        else   { asm volatile("s_waitcnt vmcnt(0)" ::: "memory"); }
        __builtin_amdgcn_s_barrier(); SBAR;
        // ph3: t1 mh0
        lda(As1, 0); ldb(Bs1);
        if (F) { stg(Wm, n0, ko2, Bs0, 2); stg(Am, m0, ko2, As0, 1); }
        PHB; MM16(0); PHB;
        // ph4: t1 mh1; boundary B
        lda(As1, 1);
        if (F) stg(Am, m0, ko3, As1, 0);
        PHB; MM16(1);
        SBAR;
        if (F) { asm volatile("s_waitcnt vmcnt(2)" ::: "memory"); }
        __builtin_amdgcn_s_barrier(); SBAR;
    }
}

// XCD swizzle for 256-block planes (256 % 8 == 0, bijective): consecutive
// work-ids (sharing A/W panels) land on the same XCD's L2.
DEVI void gemm_bid(int& m0, int& n0) {
    int bid = blockIdx.y * 8 + blockIdx.x;
    int b2 = (bid & 7) * 32 + (bid >> 3);
    m0 = (b2 >> 3) * 256;
    n0 = (b2 & 7) * 128;
}

// ---------------------------------------------------------------------------
// Batched QKV GEMM: z=0: qh=(q@wq^T+bq)*Q_SCALE  [B,H,S,DK]
//                   z=1: kh= k@wk^T+bk           [B,H,S,DK]
//                   z=2: vht=(v@wv^T+bv)^T       [B,H,DK,S]
// ---------------------------------------------------------------------------
__global__ __launch_bounds__(512, 2) void gemm_qkv(
    const unsigned short* __restrict__ aq, const unsigned short* __restrict__ ak,
    const unsigned short* __restrict__ av, const unsigned short* __restrict__ wqkv,
    const float* __restrict__ bq, const float* __restrict__ bk,
    const float* __restrict__ bv, unsigned short* __restrict__ qh,
    unsigned short* __restrict__ kh, unsigned short* __restrict__ vht) {
    const int tid = threadIdx.x;
    const int wid = tid >> 6, l = tid & 63, l16 = l & 15, quad = l >> 4;
    const int wm = (wid >> 2) * 128, wn = (wid & 3) * 32;
    int m0, n0;
    gemm_bid(m0, n0);
    const int z = blockIdx.z;
    const unsigned short* Am = z == 0 ? aq : z == 1 ? ak : av;
    const unsigned short* Wm = wqkv + (long)z * 1048576;
    const float* bias = z == 0 ? bq : z == 1 ? bk : bv;

    f32x4 acc[8][2] = {};
    gemm_core(Am, Wm, m0, n0, tid, acc);

    if (z < 2) {
        unsigned short* out = z == 0 ? qh : kh;
        const float scale = z == 0 ? Q_SCALE : 1.0f;
        #pragma unroll
        for (int ni = 0; ni < 2; ++ni) {
            int n = n0 + wn + ni * 16 + l16;
            float bvl = bias[n];
            int hh = n >> 6, dd = n & 63;
            #pragma unroll
            for (int mi = 0; mi < 8; ++mi)
                #pragma unroll
                for (int r = 0; r < 4; ++r) {
                    int m = m0 + wm + mi * 16 + quad * 4 + r;
                    int bb = m >> 11, ss = m & 2047;
                    out[(((long)(bb * NH + hh) * S_LEN + ss) * DK) + dd] =
                        f2b((acc[mi][ni][r] + bvl) * scale);
                }
        }
    } else {
        #pragma unroll
        for (int ni = 0; ni < 2; ++ni) {
            int n = n0 + wn + ni * 16 + l16;
            float bvl = bias[n];
            int hh = n >> 6, dd = n & 63;
            #pragma unroll
            for (int mi = 0; mi < 8; ++mi) {
                int m = m0 + wm + mi * 16 + quad * 4;  // r contiguous in s
                int bb = m >> 11, ss = m & 2047;
                uint2 pk;
                pk.x = pkbf16(acc[mi][ni][0] + bvl, acc[mi][ni][1] + bvl);
                pk.y = pkbf16(acc[mi][ni][2] + bvl, acc[mi][ni][3] + bvl);
                *(uint2*)(vht + ((long)(bb * NH + hh) * DK + dd) * S_LEN + ss) = pk;
            }
        }
    }
}

// ---------------------------------------------------------------------------
// Output GEMM: fp32 out[m,n] = ctx@wo^T + bo
// ---------------------------------------------------------------------------
__global__ __launch_bounds__(512, 2) void gemm_out(
    const unsigned short* __restrict__ A, const unsigned short* __restrict__ W,
    const float* __restrict__ bias, float* __restrict__ out) {
    const int tid = threadIdx.x;
    const int wid = tid >> 6, l = tid & 63, l16 = l & 15, quad = l >> 4;
    const int wm = (wid >> 2) * 128, wn = (wid & 3) * 32;
    int m0, n0;
    gemm_bid(m0, n0);

    f32x4 acc[8][2] = {};
    gemm_core(A, W, m0, n0, tid, acc);

    #pragma unroll
    for (int ni = 0; ni < 2; ++ni) {
        int n = n0 + wn + ni * 16 + l16;
        float bv = bias[n];
        #pragma unroll
        for (int mi = 0; mi < 8; ++mi)
            #pragma unroll
            for (int r = 0; r < 4; ++r) {
                int m = m0 + wm + mi * 16 + quad * 4 + r;
                out[(long)m * 1024 + n] = acc[mi][ni][r] + bv;
            }
    }
}

// ---------------------------------------------------------------------------
// Flash attention — R3 version verbatim (proven 108.9-110.8 us).
// Transposed formulation: S^T = K.Q^T; p = exp2(s); P via wave-private LDS
// rows; O^T = V^T.P^T; lsum via ones-vector MFMA; K dbuf staged 1 ahead,
// V tri-buf staged 2 ahead; counted vmcnt(2) + raw barrier once per kt.
// LDS: 16384 (Kb x2) + 24576 (Vb x3) + 11264 (P) = 52224 B -> 3 blocks/CU.
// ---------------------------------------------------------------------------
__global__ __launch_bounds__(256, 3) void attn(
    const unsigned short* __restrict__ qh, const unsigned short* __restrict__ kh,
    const unsigned short* __restrict__ vht, unsigned short* __restrict__ ctx) {
    __shared__ __align__(16) unsigned short Kb[2][4096];   // [64 keys][64 d] swz
    __shared__ __align__(16) unsigned short Vb[3][4096];   // [64 d][64 keys] swz
    __shared__ __align__(16) unsigned short P[128 * 44];

    // XCD-aware swizzle: 1024 blocks, bijective; 128 blocks/XCD = 8 heads
    // x 16 q-tiles (head's K/V panel L2-resident). R1: FETCH 139->32 MB.
    const int id = blockIdx.y * 16 + blockIdx.x;
    const int id2 = (id & 7) * 128 + (id >> 3);
    const int qt = id2 & 15, bh = id2 >> 4;
    const int tid = threadIdx.x;
    const int w = tid >> 6, l = tid & 63, l16 = l & 15, quad = l >> 4;

    const unsigned short* kh_b = kh + (long)bh * 2048 * 64;
    const unsigned short* vh_b = vht + (long)bh * 64 * 2048;

    const unsigned short* qsrc = qh + ((long)bh * 2048 + qt * 128) * 64;
    bf16x8 qf[2][2];
    #pragma unroll
    for (int dd = 0; dd < 2; ++dd)
        #pragma unroll
        for (int i = 0; i < 2; ++i)
            qf[dd][i] = *(const bf16x8*)(qsrc + (w * 32 + i * 16 + l16) * 64 +
                                         dd * 32 + quad * 8);
    #pragma unroll
    for (int dd = 0; dd < 2; ++dd)
        #pragma unroll
        for (int i = 0; i < 2; ++i)
            asm volatile("" :: "v"(qf[dd][i]));

    auto stage_k = [&](const unsigned short* base, int buf) {
        #pragma unroll
        for (int rr = 0; rr < 2; ++rr) {
            int sb = rr * 256 + w * 64;
            int slot = sb + l;
            int row = slot >> 3, cc = (slot & 7) ^ (row & 7);
            GLL16(base + (long)row * 64 + cc * 8, &Kb[buf][sb * 8]);
        }
    };
    auto stage_v = [&](const unsigned short* vbase, int buf) {
        #pragma unroll
        for (int rr = 0; rr < 2; ++rr) {
            int sb = rr * 256 + w * 64;
            int slot = sb + l;
            int d = slot >> 3, cc = (slot & 7) ^ (d & 7);
            GLL16(vbase + (long)d * 2048 + cc * 8, &Vb[buf][sb * 8]);
        }
    };

    // prologue: K0, V0, V1 issued; wait K0+V0 (vmcnt(2) leaves V1 in flight)
    stage_k(kh_b, 0);
    stage_v(vh_b, 0);
    stage_v(vh_b + 64, 1);
    asm volatile("s_waitcnt vmcnt(2)" ::: "memory");
    __builtin_amdgcn_s_barrier();
    __builtin_amdgcn_sched_barrier(0);

    f32x4 o[4][2] = {};
    f32x4 osum[2] = {};
    bf16x8 ones;
    #pragma unroll
    for (int j = 0; j < 8; ++j) ones[j] = (short)0x3f80;  // bf16 1.0

    const unsigned short* kstage = kh_b + 64 * 64;   // K[1] base
    const unsigned short* vstage = vh_b + 2 * 64;    // V[2] base
    int vr = 0, vs = 2;  // V read / stage buffer (mod 3)
    for (int kt = 0; kt < 32; ++kt) {
        if (kt < 31) stage_k(kstage, (kt + 1) & 1);
        if (kt < 30) stage_v(vstage, vs);
        kstage += 64 * 64;
        vstage += 64;
        __builtin_amdgcn_sched_barrier(0);  // keep prefetch issue at loop top

        const unsigned short* kb = Kb[kt & 1];
        f32x4 sa[2][4] = {};
        #pragma unroll
        for (int dd = 0; dd < 2; ++dd) {
            bf16x8 kf[4];
            #pragma unroll
            for (int ja = 0; ja < 4; ++ja) {
                int row = ja * 16 + l16;
                kf[ja] = *(const bf16x8*)(kb + (row * 8 + ((dd * 4 + quad) ^ (row & 7))) * 8);
            }
            __builtin_amdgcn_s_setprio(1);
            #pragma unroll
            for (int i = 0; i < 2; ++i)
                #pragma unroll
                for (int ja = 0; ja < 4; ++ja)
                    sa[i][ja] = mfma16(kf[ja], qf[dd][i], sa[i][ja]);
            __builtin_amdgcn_s_setprio(0);
        }

        #pragma unroll
        for (int i = 0; i < 2; ++i)
            #pragma unroll
            for (int ja = 0; ja < 4; ++ja)
                #pragma unroll
                for (int r = 0; r < 4; ++r)
                    sa[i][ja][r] = fexp2(sa[i][ja][r]);

        // no barrier: V[kt] resident since end of kt-1; Vb[vs] is a
        // different buffer ((kt+2)%3 != kt%3).
        const unsigned short* vb = Vb[vr];
        #pragma unroll
        for (int qtr = 0; qtr < 2; ++qtr) {
            #pragma unroll
            for (int jh = 0; jh < 2; ++jh)
                #pragma unroll
                for (int i = 0; i < 2; ++i) {
                    int row = w * 32 + i * 16 + l16;
                    int ja = qtr * 2 + jh;
                    uint2 pk;
                    pk.x = pkbf16(sa[i][ja][0], sa[i][ja][1]);
                    pk.y = pkbf16(sa[i][ja][2], sa[i][ja][3]);
                    *(uint2*)(&P[row * 44 + jh * 16 + quad * 4]) = pk;
                }
            bf16x8 vf[4], pf[2];
            #pragma unroll
            for (int jd = 0; jd < 4; ++jd) {
                int d = jd * 16 + l16;
                vf[jd] = *(const bf16x8*)(vb + (d * 8 + ((qtr * 4 + quad) ^ (d & 7))) * 8);
            }
            #pragma unroll
            for (int i = 0; i < 2; ++i) {
                int row = w * 32 + i * 16 + l16;
                pf[i] = *(const bf16x8*)(&P[row * 44 + quad * 8]);
            }
            __builtin_amdgcn_s_setprio(1);
            #pragma unroll
            for (int jd = 0; jd < 4; ++jd)
                #pragma unroll
                for (int i = 0; i < 2; ++i)
                    o[jd][i] = mfma16(vf[jd], pf[i], o[jd][i]);
            #pragma unroll
            for (int i = 0; i < 2; ++i)
                osum[i] = mfma16(ones, pf[i], osum[i]);  // row-sum on MFMA pipe
            __builtin_amdgcn_s_setprio(0);
        }

        // end-of-kt sync: wait K[kt+1]+V[kt+1] landed, keep V[kt+2] in flight
        if (kt < 30) {
            asm volatile("s_waitcnt vmcnt(2)" ::: "memory");
        } else if (kt == 30) {
            asm volatile("s_waitcnt vmcnt(0)" ::: "memory");
        }
        if (kt < 31) {
            __builtin_amdgcn_s_barrier();
            __builtin_amdgcn_sched_barrier(0);
        }

        vr = (vr + 1 == 3) ? 0 : vr + 1;
        vs = (vs + 1 == 3) ? 0 : vs + 1;
    }

    const int b = bh >> 4, hh = bh & 15;
    #pragma unroll
    for (int i = 0; i < 2; ++i) {
        float inv = 1.0f / osum[i][0];  // rows of osum all equal; col = l16 = q
        int s = qt * 128 + w * 32 + i * 16 + l16;
        #pragma unroll
        for (int jd = 0; jd < 4; ++jd) {
            uint2 pk;
            pk.x = pkbf16(o[jd][i][0] * inv, o[jd][i][1] * inv);
            pk.y = pkbf16(o[jd][i][2] * inv, o[jd][i][3] * inv);
            *(uint2*)(&ctx[((long)(b * 2048 + s) * 1024) + hh * 64 + jd * 16 + quad * 4]) = pk;
        }
    }
}

extern "C" void kernel_launch(void* const* d_in, const int* in_sizes, int n_in,
                              void* d_out, int out_size, void* d_ws, size_t ws_size,
                              hipStream_t stream) {
    const float* q  = (const float*)d_in[0];
    const float* k  = (const float*)d_in[1];
    const float* v  = (const float*)d_in[2];
    const float* wq = (const float*)d_in[3];
    const float* bq = (const float*)d_in[4];
    const float* wk = (const float*)d_in[5];
    const float* bk = (const float*)d_in[6];
    const float* wv = (const float*)d_in[7];
    const float* bv = (const float*)d_in[8];
    const float* wo = (const float*)d_in[9];
    const float* bo = (const float*)d_in[10];
    float* out = (float*)d_out;

    // workspace (u16 units): ab_q(8M, reused as ctx) | qh(8M) | kh(8M) |
    // vht(8M) | weights 4x1M  = 36M u16 = 72 MB.
    // ab_k/ab_v live in d_out (32 MB fp32 = 16M u16), dead until gemm_out.
    const size_t NE = 8u * 1024u * 1024u;
    unsigned short* ab_q = (unsigned short*)d_ws;
    unsigned short* qh   = ab_q + NE;
    unsigned short* kh   = qh + NE;
    unsigned short* vht  = kh + NE;
    unsigned short* wb   = vht + NE;
    unsigned short* wob  = wb + 3 * 1048576;
    unsigned short* ctx  = ab_q;
    unsigned short* ab_k = (unsigned short*)d_out;
    unsigned short* ab_v = ab_k + NE;

    cvt_all<<<dim3(14336), dim3(256), 0, stream>>>(q, k, v, wq, wk, wv, wo,
                                                   ab_q, ab_k, ab_v, wb);
    gemm_qkv<<<dim3(8, 32, 3), dim3(512), 0, stream>>>(ab_q, ab_k, ab_v, wb,
                                                       bq, bk, bv, qh, kh, vht);
    attn<<<dim3(16, 64), dim3(256), 0, stream>>>(qh, kh, vht, ctx);
    gemm_out<<<dim3(8, 32), dim3(512), 0, stream>>>(ctx, wob, bo, out);
}